// Round 5
// baseline (353.251 us; speedup 1.0000x reference)
//
#include <hip/hip_runtime.h>
#include <hip/hip_bf16.h>

// Problem constants (fixed by the reference setup):
//   B=2000 graphs, LGPG=100 line-graph nodes/graph, NPG=20 nodes/graph,
//   ELPG=10 labeled edges/graph, D=300, HDIM=100 -> split at col 200.
#define D_      300
#define D2_     150       // D/2 float2s per row
#define H2_     200       // 2*HDIM: cols [0,200) <- incoming, [200,300) <- outgoing
#define NPGMAX  20
#define ROWMAX  128
#define BN_     2000
#define NNODES_ 40000
#define ELAB_   20000

__global__ __launch_bounds__(256) void main_kernel(
    const float* __restrict__ x, const int* __restrict__ lgidx,
    const int* __restrict__ ptr, const int* __restrict__ ogs,
    const int* __restrict__ els, const int* __restrict__ edge_in,
    float* __restrict__ out)
{
    // Output layout (element offsets into the flat FLOAT32 buffer):
    //   x_new   [40000,300] @ 0
    //   edge    [2,20000]   @ 12,000,000
    //   ptr_new [2001]      @ 12,040,000
    //   batch   [40000]     @ 12,042,001
    float* __restrict__ out_x     = out;
    float* __restrict__ out_edge  = out + (size_t)NNODES_ * D_;
    float* __restrict__ out_ptr   = out + (size_t)NNODES_ * D_ + 2 * ELAB_;
    float* __restrict__ out_batch = out + (size_t)NNODES_ * D_ + 2 * ELAB_ + (BN_ + 1);

    __shared__ float acc[NPGMAX * D_];     // 24 KB
    __shared__ int   cin[NPGMAX], cou[NPGMAX];
    __shared__ int   sidx[ROWMAX * 2];
    __shared__ int   s_r1[256], s_r2[256];

    const int g = blockIdx.x;
    const int t = threadIdx.x;

    // ---- Per-block exclusive prefix sums over ogs/els (no workspace). ----
    int p1 = 0, p2 = 0;
    for (int k = t; k < g; k += 256) { p1 += ogs[k]; p2 += els[k]; }
    s_r1[t] = p1; s_r2[t] = p2;
    __syncthreads();
    for (int s = 128; s > 0; s >>= 1) {
        if (t < s) { s_r1[t] += s_r1[t + s]; s_r2[t] += s_r2[t + s]; }
        __syncthreads();
    }
    const int nbase = s_r1[0];   // = sum ogs[0..g)
    const int eb    = s_r2[0];   // = sum els[0..g)
    __syncthreads();

    const int lg0 = ptr[g], lg1 = ptr[g + 1];
    int nrow = lg1 - lg0; if (nrow > ROWMAX) nrow = ROWMAX; if (nrow < 0) nrow = 0;
    const int npg_true = ogs[g];
    int npg = npg_true; if (npg > NPGMAX) npg = NPGMAX;

    for (int i = t; i < NPGMAX * D_; i += 256) acc[i] = 0.0f;
    if (t < NPGMAX) { cin[t] = 0; cou[t] = 0; }
    for (int i = t; i < nrow * 2; i += 256) sidx[i] = lgidx[(size_t)lg0 * 2 + i];
    __syncthreads();

    if (t < nrow) {
        atomicAdd(&cou[sidx[2 * t]], 1);       // int LDS atomics: native ds_add_u32
        atomicAdd(&cin[sidx[2 * t + 1]], 1);
    }

    // Flat float2 sweep over this graph's x slice: nrow*150 float2s, contiguous.
    // unsafeAtomicAdd -> native ds_add_f32 (no CAS loop). Lane addr stride = 2
    // banks -> 4-way conflict (~free per m136).
    const int nf2 = nrow * D2_;
    const float2* xs = (const float2*)(x + (size_t)lg0 * D_);
    for (int f = t; f < nf2; f += 256) {
        float2 v = xs[f];
        int row = f / D2_;
        int c2  = f - row * D2_;
        int col = c2 * 2;                       // split at 200 is float2-aligned
        int seg = (col < H2_) ? sidx[2 * row + 1] : sidx[2 * row];
        float* a = &acc[seg * D_ + col];
        unsafeAtomicAdd(a + 0, v.x);
        unsafeAtomicAdd(a + 1, v.y);
    }
    __syncthreads();

    // Epilogue: mean + f32 store, float2-vectorized.
    // Global elem offset = nbase*300 + 2*i2 (even), float2 idx = nbase*150 + i2.
    float2* out_x2 = (float2*)out_x;
    const size_t obase2 = (size_t)nbase * D2_;
    for (int i2 = t; i2 < npg * D2_; i2 += 256) {
        int n  = i2 / D2_;
        int c2 = i2 - n * D2_;
        int c  = 2 * c2;
        int cnt = (c < H2_) ? cin[n] : cou[n];
        float inv = (cnt > 0) ? 1.0f / (float)cnt : 0.0f;
        float2 o;
        o.x = acc[n * D_ + c] * inv;
        o.y = acc[n * D_ + c + 1] * inv;
        out_x2[obase2 + i2] = o;
    }

    // Small outputs, piggybacked per graph.
    if (t == 0) {
        out_ptr[g + 1] = (float)(nbase + npg_true);
        if (g == 0) out_ptr[0] = 0.0f;
    }
    for (int i = t; i < npg_true; i += 256)
        out_batch[nbase + i] = (float)g;

    const int nel = els[g];
    const int lgoff = lg0 - ptr[0];
    for (int j = t; j < nel; j += 256) {
        out_edge[eb + j]                 = (float)(edge_in[eb + j] - lgoff);
        out_edge[(size_t)ELAB_ + eb + j] = (float)(edge_in[(size_t)ELAB_ + eb + j] - lgoff);
    }
}

extern "C" void kernel_launch(void* const* d_in, const int* in_sizes, int n_in,
                              void* d_out, int out_size, void* d_ws, size_t ws_size,
                              hipStream_t stream)
{
    const float* x        = (const float*)d_in[0];
    const int*   lgidx    = (const int*)d_in[1];
    const int*   ptr      = (const int*)d_in[2];
    const int*   ogs      = (const int*)d_in[3];
    const int*   els      = (const int*)d_in[4];
    const int*   edge_in  = (const int*)d_in[5];

    main_kernel<<<BN_, 256, 0, stream>>>(x, lgidx, ptr, ogs, els, edge_in,
                                         (float*)d_out);
}

// Round 6
// 97.770 us; speedup vs baseline: 3.6131x; 3.6131x over previous
//
#include <hip/hip_runtime.h>
#include <hip/hip_bf16.h>

// B=2000 graphs, LGPG=100 line-graph nodes/graph, NPG=20, ELPG=10, D=300.
#define D_      300
#define H2_     200       // cols [0,200) <- incoming (idx[:,1]), [200,300) <- outgoing (idx[:,0])
#define NPGMAX  20
#define ROWMAX  128
#define BN_     2000
#define NNODES_ 40000
#define ELAB_   20000
#define TPB_    320       // 5 waves; threads 0..299 own one column each

__global__ __launch_bounds__(TPB_) void main_kernel(
    const float* __restrict__ x, const int* __restrict__ lgidx,
    const int* __restrict__ ptr, const int* __restrict__ ogs,
    const int* __restrict__ els, const int* __restrict__ edge_in,
    float* __restrict__ out)
{
    // Output layout (f32 element offsets): x_new@0 [40000,300], edge@12,000,000 [2,20000],
    // ptr_new@12,040,000 [2001], batch@12,042,001 [40000].
    float* __restrict__ out_x     = out;
    float* __restrict__ out_edge  = out + (size_t)NNODES_ * D_;
    float* __restrict__ out_ptr   = out + (size_t)NNODES_ * D_ + 2 * ELAB_;
    float* __restrict__ out_batch = out + (size_t)NNODES_ * D_ + 2 * ELAB_ + (BN_ + 1);

    __shared__ int sidx[ROWMAX * 2];
    __shared__ int pool_in[ROWMAX], pool_out[ROWMAX];
    __shared__ int cnt_in[NPGMAX], cnt_out[NPGMAX];
    __shared__ int off_in[NPGMAX + 1], off_out[NPGMAX + 1];
    __shared__ int s_r1[256], s_r2[256];

    const int g = blockIdx.x;
    const int t = threadIdx.x;

    // ---- Exclusive prefix of ogs/els over graphs [0,g) (256 participants). ----
    if (t < 256) {
        int p1 = 0, p2 = 0;
        for (int k = t; k < g; k += 256) { p1 += ogs[k]; p2 += els[k]; }
        s_r1[t] = p1; s_r2[t] = p2;
    }
    __syncthreads();
    for (int s = 128; s > 0; s >>= 1) {
        if (t < s) { s_r1[t] += s_r1[t + s]; s_r2[t] += s_r2[t + s]; }
        __syncthreads();
    }
    const int nbase = s_r1[0];
    const int eb    = s_r2[0];

    const int lg0 = ptr[g], lg1 = ptr[g + 1];
    int nrow = lg1 - lg0; if (nrow > ROWMAX) nrow = ROWMAX; if (nrow < 0) nrow = 0;
    const int npg_true = ogs[g];
    int npg = npg_true; if (npg > NPGMAX) npg = NPGMAX;
    __syncthreads();

    if (t < NPGMAX) { cnt_in[t] = 0; cnt_out[t] = 0; }
    for (int i = t; i < nrow * 2; i += TPB_) sidx[i] = lgidx[(size_t)lg0 * 2 + i];
    __syncthreads();

    if (t < nrow) {
        atomicAdd(&cnt_out[sidx[2 * t]], 1);      // native ds_add_u32, commutative -> deterministic
        atomicAdd(&cnt_in[sidx[2 * t + 1]], 1);
    }
    __syncthreads();

    if (t == 0) {
        int a = 0, b = 0;
        for (int n = 0; n < NPGMAX; ++n) {
            off_in[n] = a;  a += cnt_in[n];
            off_out[n] = b; b += cnt_out[n];
        }
        off_in[NPGMAX] = a; off_out[NPGMAX] = b;
    }
    __syncthreads();

    // Deterministic CSR fill: slot = off[n] + #{r' < r : seg(r')==n}.
    if (t < nrow) {
        const int nin = sidx[2 * t + 1], nou = sidx[2 * t];
        int pin = 0, pou = 0;
        for (int r = 0; r < t; ++r) {
            pin += (sidx[2 * r + 1] == nin);
            pou += (sidx[2 * r]     == nou);
        }
        pool_in[off_in[nin] + pin]   = t;
        pool_out[off_out[nou] + pou] = t;
    }
    __syncthreads();

    // ---- Main gather: thread t owns column c=t; register accumulation. ----
    if (t < D_) {
        const int c = t;
        const bool inc = (c < H2_);
        const int* __restrict__ pool = inc ? pool_in : pool_out;
        const int* __restrict__ off  = inc ? off_in  : off_out;
        const float* __restrict__ xg = x + (size_t)lg0 * D_ + c;
        const size_t obase = (size_t)nbase * D_ + c;
        for (int n = 0; n < npg; ++n) {
            const int lo = off[n], hi = off[n + 1];
            float s = 0.0f;
            int k = lo;
            for (; k + 1 < hi; k += 2)            // 2 loads in flight per step
                s += xg[pool[k] * D_] + xg[pool[k + 1] * D_];
            if (k < hi) s += xg[pool[k] * D_];
            out_x[obase + (size_t)n * D_] = (hi > lo) ? s / (float)(hi - lo) : 0.0f;
        }
    }

    // ---- Small outputs. ----
    if (t == 0) {
        out_ptr[g + 1] = (float)(nbase + npg_true);
        if (g == 0) out_ptr[0] = 0.0f;
    }
    for (int i = t; i < npg_true; i += TPB_)
        out_batch[nbase + i] = (float)g;

    const int nel = els[g];
    const int lgoff = lg0 - ptr[0];
    for (int j = t; j < nel; j += TPB_) {
        out_edge[eb + j]                 = (float)(edge_in[eb + j] - lgoff);
        out_edge[(size_t)ELAB_ + eb + j] = (float)(edge_in[(size_t)ELAB_ + eb + j] - lgoff);
    }
}

extern "C" void kernel_launch(void* const* d_in, const int* in_sizes, int n_in,
                              void* d_out, int out_size, void* d_ws, size_t ws_size,
                              hipStream_t stream)
{
    const float* x        = (const float*)d_in[0];
    const int*   lgidx    = (const int*)d_in[1];
    const int*   ptr      = (const int*)d_in[2];
    const int*   ogs      = (const int*)d_in[3];
    const int*   els      = (const int*)d_in[4];
    const int*   edge_in  = (const int*)d_in[5];

    main_kernel<<<BN_, TPB_, 0, stream>>>(x, lgidx, ptr, ogs, els, edge_in,
                                          (float*)d_out);
}